// Round 7
// baseline (189.003 us; speedup 1.0000x reference)
//
#include <hip/hip_runtime.h>
#include <stdint.h>

// Problem constants (from reference)
#define B_SZ   512
#define T_SZ   100
#define NPRE   256
#define NPOST  256
#define KTOT   (B_SZ * T_SZ)   // 51200

typedef __bf16 bf16x8 __attribute__((ext_vector_type(8)));
typedef float  floatx4 __attribute__((ext_vector_type(4)));

__device__ __forceinline__ uint32_t bf16_rne(float v) {
    uint32_t bits = __float_as_uint(v);
    return (bits + 0x7FFFu + ((bits >> 16) & 1u)) >> 16;
}
__device__ __forceinline__ uint32_t pack_trunc2(float a, float b) {
    return (__float_as_uint(a) >> 16) | (__float_as_uint(b) & 0xFFFF0000u);
}

// ---------------------------------------------------------------------------
// R18 = R15 (deep load pipelining over the proven R10 structure) with the
// register budget ACTUALLY granted: __launch_bounds__(256, 2) (the R10-proven
// spelling; min 2 waves/EU -> 256-VGPR budget). R15's amdgpu_waves_per_eu(2)
// attribute did NOT raise the cap (VGPR_Count pinned at exactly 128 + 178 MB
// scratch): right schedule, wrong budget. Peak live ~140 floats fits in 256.
// Occupancy unchanged: LDS 64 KB caps at 2 blocks/CU = 8 waves/CU, and
// VGPR<=256 still allows 8 waves/CU.
//
// Theory being tested (R10 audit): fused time is per-wave serial load-latency
// chains (~400 one-at-a-time exposures x ~500 cy); batch-issue + prefetch
// cuts exposures ~10x. sched_barrier(0) pins issue clusters (proven honored
// by R15's spill).  Mapping, LDS layout, arithmetic order, partial layout,
// reduces: bit-identical to R10.
// ---------------------------------------------------------------------------
__device__ __forceinline__ void issue_x(const float* src, int tbase, int n, float* x) {
#pragma unroll
    for (int j = 0; j < n; ++j)
        x[j] = src[(size_t)(tbase + j) * NPRE];
}

__device__ __forceinline__ void consume16(const float* x, float& carry,
                                          uint32_t* pkc, float decay) {
#pragma unroll
    for (int j = 0; j < 16; ++j) {
        uint32_t lo = bf16_rne(carry);   // trace[t]=carry, then update
        carry = decay * (carry + x[2 * j]);
        uint32_t hi = bf16_rne(carry);
        carry = decay * (carry + x[2 * j + 1]);
        pkc[j] = lo | (hi << 16);
    }
}

__device__ __forceinline__ void deposit_A(unsigned short (*A)[512],
                                          const uint32_t* pk, int pg, int lp)
{
#pragma unroll
    for (int kc = 0; kc < 3; ++kc)
#pragma unroll
        for (int w = 0; w < 4; ++w)
            *(uint4*)&A[kc * 8 + pg][(w * 16 + lp) * 8] =
                make_uint4(pk[kc * 16 + w * 4],     pk[kc * 16 + w * 4 + 1],
                           pk[kc * 16 + w * 4 + 2], pk[kc * 16 + w * 4 + 3]);
    // kc = 3: t 96..99 real, 100..127 zero
    *(uint4*)&A[24 + pg][lp * 8] = make_uint4(pk[48], pk[49], 0u, 0u);
#pragma unroll
    for (int w = 1; w < 4; ++w)
        *(uint4*)&A[24 + pg][(w * 16 + lp) * 8] = make_uint4(0u, 0u, 0u, 0u);
}

// B staging split: LOAD issues early (regs), STORE packs late (R10's exact
// pack/store code). half==0 -> t 0..47 (48 loads); half==1 -> t 48..99 (52).
__device__ __forceinline__ void load_B(const float* pb, int half, float* x) {
    if (half == 0) {
#pragma unroll
        for (int j = 0; j < 48; ++j)
            x[j] = pb[(size_t)j * NPOST];
    } else {
#pragma unroll
        for (int j = 0; j < 52; ++j)
            x[j] = pb[(size_t)(48 + j) * NPOST];
    }
}
__device__ __forceinline__ void store_B(unsigned short (*Bl)[512], int half,
                                        int qg, int q15, const float* x)
{
    if (half == 0) {
#pragma unroll
        for (int o = 0; o < 6; ++o)   // octs 0..5: t 0..47
            *(uint4*)&Bl[(o >> 2) * 8 + qg][((o & 3) * 16 + q15) * 8] =
                make_uint4(pack_trunc2(x[o * 8 + 0], x[o * 8 + 1]),
                           pack_trunc2(x[o * 8 + 2], x[o * 8 + 3]),
                           pack_trunc2(x[o * 8 + 4], x[o * 8 + 5]),
                           pack_trunc2(x[o * 8 + 6], x[o * 8 + 7]));
    } else {
#pragma unroll
        for (int o = 6; o < 12; ++o) {  // octs 6..11: t 48..95
            int u = o * 8 - 48;
            *(uint4*)&Bl[(o >> 2) * 8 + qg][((o & 3) * 16 + q15) * 8] =
                make_uint4(pack_trunc2(x[u + 0], x[u + 1]),
                           pack_trunc2(x[u + 2], x[u + 3]),
                           pack_trunc2(x[u + 4], x[u + 5]),
                           pack_trunc2(x[u + 6], x[u + 7]));
        }
        // oct 12: t 96..99 real + zeros; octs 13..15: zero
        *(uint4*)&Bl[24 + qg][q15 * 8] =
            make_uint4(pack_trunc2(x[48], x[49]), pack_trunc2(x[50], x[51]), 0u, 0u);
#pragma unroll
        for (int o = 13; o < 16; ++o)
            *(uint4*)&Bl[24 + qg][((o & 3) * 16 + q15) * 8] =
                make_uint4(0u, 0u, 0u, 0u);
    }
}

__global__ __launch_bounds__(256, 2) void stdp_fused_gemm(
    const float* __restrict__ pre, const float* __restrict__ post,
    float* __restrict__ partial)
{
    __shared__ __align__(16) unsigned short A_lds[32][512];  // 32 KB
    __shared__ __align__(16) unsigned short B_lds[32][512];  // 32 KB

    const int bx   = blockIdx.x;      // 0..511
    const int s    = bx & 127;
    const int tile = bx >> 7;         // 0..3
    const int pt   = tile & 1;
    const int qt   = tile >> 1;
    const int tid  = threadIdx.x;     // 0..255
    const int lane = tid & 63, wave = tid >> 6;   // wave = wp (0..3)
    const int l15 = lane & 15, l4 = lane >> 4;

    const int half  = tid >> 7;       // 0/1 (wave-uniform): scan batch / B t-half
    const int p_loc = tid & 127;      // scan row
    const int qloc  = tid & 127;      // B column
    const int qg = qloc >> 4, q15 = qloc & 15;
    const int pg = p_loc >> 4, lp = p_loc & 15;

    const float decay = 0.95122942450071400910f;   // expf(-1/20)

    floatx4 acc[2][8] = {};

    float x0[32], x1[32], x2[36], xb[52];
    uint32_t pk[50];

    // ---- initial scan-load issue for round 0 (t 0..63 in flight) ----
    {
        const int b = s * 4 + half;
        const float* src = pre + (size_t)b * (T_SZ * NPRE) + pt * 128 + p_loc;
        issue_x(src, 0, 32, x0);
        __builtin_amdgcn_sched_barrier(0);
        issue_x(src, 32, 32, x1);
        __builtin_amdgcn_sched_barrier(0);
    }

#pragma unroll
    for (int r = 0; r < 2; ++r) {
        const int b_scan = s * 4 + 2 * r + half;
        const float* src = pre + (size_t)b_scan * (T_SZ * NPRE) + pt * 128 + p_loc;
        float carry = 0.0f;

        // consume t0..31 while t32..63 in flight
        consume16(x0, carry, &pk[0], decay);
        // issue t64..99 (36 loads)
        issue_x(src, 64, 36, x2);
        __builtin_amdgcn_sched_barrier(0);
        // consume t32..63 while t64..99 in flight
        consume16(x1, carry, &pk[16], decay);
        // issue B loads for phase lh=0 (batch 2r+0)
        load_B(post + (size_t)(s * 4 + 2 * r) * (T_SZ * NPOST) + qt * 128 + qloc,
               half, xb);
        __builtin_amdgcn_sched_barrier(0);
        // consume t64..95 and tail t96..99
        consume16(x2, carry, &pk[32], decay);
#pragma unroll
        for (int j = 0; j < 2; ++j) {
            uint32_t lo = bf16_rne(carry);
            carry = decay * (carry + x2[32 + 2 * j]);
            uint32_t hi = bf16_rne(carry);
            carry = decay * (carry + x2[32 + 2 * j + 1]);
            pk[48 + j] = lo | (hi << 16);
        }

        // ---- phase 0 (batch 2r+0) ----
        if (half == 0) deposit_A(A_lds, pk, pg, lp);
        store_B(B_lds, half, qg, q15, xb);
        __syncthreads();

        // issue B loads for phase 1 (batch 2r+1): in flight across MFMA0
        load_B(post + (size_t)(s * 4 + 2 * r + 1) * (T_SZ * NPOST) + qt * 128 + qloc,
               half, xb);
        __builtin_amdgcn_sched_barrier(0);

#pragma unroll
        for (int kc = 0; kc < 4; ++kc) {
            bf16x8 a[2], bb[8];
#pragma unroll
            for (int f = 0; f < 2; ++f)
                a[f] = *(const bf16x8*)&A_lds[kc * 8 + wave * 2 + f][lane * 8];
#pragma unroll
            for (int g = 0; g < 8; ++g)
                bb[g] = *(const bf16x8*)&B_lds[kc * 8 + g][lane * 8];
#pragma unroll
            for (int f = 0; f < 2; ++f)
#pragma unroll
                for (int g = 0; g < 8; ++g)
                    acc[f][g] = __builtin_amdgcn_mfma_f32_16x16x32_bf16(
                        a[f], bb[g], acc[f][g], 0, 0, 0);
        }
        __syncthreads();

        // ---- phase 1 (batch 2r+1) ----
        if (half == 1) deposit_A(A_lds, pk, pg, lp);
        store_B(B_lds, half, qg, q15, xb);
        __syncthreads();

        // prefetch round 1's scan loads: in flight across MFMA1
        if (r == 0) {
            const int bn = s * 4 + 2 + half;
            const float* srcn = pre + (size_t)bn * (T_SZ * NPRE) + pt * 128 + p_loc;
            issue_x(srcn, 0, 32, x0);
            __builtin_amdgcn_sched_barrier(0);
            issue_x(srcn, 32, 32, x1);
            __builtin_amdgcn_sched_barrier(0);
        }

#pragma unroll
        for (int kc = 0; kc < 4; ++kc) {
            bf16x8 a[2], bb[8];
#pragma unroll
            for (int f = 0; f < 2; ++f)
                a[f] = *(const bf16x8*)&A_lds[kc * 8 + wave * 2 + f][lane * 8];
#pragma unroll
            for (int g = 0; g < 8; ++g)
                bb[g] = *(const bf16x8*)&B_lds[kc * 8 + g][lane * 8];
#pragma unroll
            for (int f = 0; f < 2; ++f)
#pragma unroll
                for (int g = 0; g < 8; ++g)
                    acc[f][g] = __builtin_amdgcn_mfma_f32_16x16x32_bf16(
                        a[f], bb[g], acc[f][g], 0, 0, 0);
        }
        __syncthreads();
    }

    // ---- writeout: partial[bx][p_loc 128][q_loc 128]
    // C/D layout (m89/m91): col = lane&15, row = (lane>>4)*4 + reg
    float* pout = partial + (size_t)bx * (128 * 128);
#pragma unroll
    for (int f = 0; f < 2; ++f) {
        int r0 = wave * 32 + f * 16 + l4 * 4;
#pragma unroll
        for (int g = 0; g < 8; ++g) {
            int c = g * 16 + l15;
#pragma unroll
            for (int v = 0; v < 4; ++v)
                pout[(size_t)(r0 + v) * 128 + c] = acc[f][g][v];
        }
    }
}

// ---------------------------------------------------------------------------
// Reduce stage 1 (R10-proven): partial[bx = tile*128 + s][i], i = p*128+q.
// 2048 blocks x 256 thr; thread t: g = t>>16 (0..7), e = t&65535,
// tile = e>>14; sums s = g*16..+15 (4 indep chains).
// ---------------------------------------------------------------------------
__global__ __launch_bounds__(256) void stdp_reduce1(
    const float* __restrict__ partial, float* __restrict__ tmp)
{
    const int t = blockIdx.x * 256 + threadIdx.x;  // 0..524287
    const int g = t >> 16;                         // 0..7
    const int e = t & 65535;
    const int tile = e >> 14;
    const float* src = partial + ((size_t)(tile * 128 + g * 16) << 14) + (e & 16383);
    float a4[4] = {};
#pragma unroll
    for (int i = 0; i < 4; ++i)
#pragma unroll
        for (int u = 0; u < 4; ++u)
            a4[u] += src[(size_t)(u * 4 + i) << 14];
    tmp[t] = (a4[0] + a4[1]) + (a4[2] + a4[3]);
}

// ---------------------------------------------------------------------------
// Reduce stage 2 (R10-proven): 8 -> 1, un-tile, scale by (A+ - A-)/(B*T).
// ---------------------------------------------------------------------------
__global__ __launch_bounds__(256) void stdp_reduce2(
    const float* __restrict__ tmp, float* __restrict__ out)
{
    const int idx = blockIdx.x * 256 + threadIdx.x;  // 0..65535
    const int P = idx >> 8, Q = idx & 255;
    const int tile = (Q >> 7) * 2 + (P >> 7);
    const int e = (tile << 14) | ((P & 127) << 7) | (Q & 127);
    float a[4];
#pragma unroll
    for (int u = 0; u < 4; ++u)
        a[u] = tmp[(size_t)(2 * u) * 65536 + e] +
               tmp[(size_t)(2 * u + 1) * 65536 + e];
    const float scale = (0.005f - 0.00525f) * (1.0f / (float)KTOT);
    out[idx] = ((a[0] + a[1]) + (a[2] + a[3])) * scale;
}

// ---------------------------------------------------------------------------
extern "C" void kernel_launch(void* const* d_in, const int* in_sizes, int n_in,
                              void* d_out, int out_size, void* d_ws, size_t ws_size,
                              hipStream_t stream)
{
    const float* pre  = (const float*)d_in[0];   // [512,100,256]
    const float* post = (const float*)d_in[1];   // [512,100,256]
    float* out = (float*)d_out;                  // [256,256]

    // ws: partial 33.5 MB | tmp 2 MB
    float* partial = (float*)d_ws;
    float* tmp     = (float*)((char*)d_ws + (size_t)33554432);

    stdp_fused_gemm<<<512, 256, 0, stream>>>(pre, post, partial);
    stdp_reduce1<<<2048, 256, 0, stream>>>(partial, tmp);
    stdp_reduce2<<<256, 256, 0, stream>>>(tmp, out);
}

// Round 8
// 158.274 us; speedup vs baseline: 1.1942x; 1.1942x over previous
//
#include <hip/hip_runtime.h>
#include <stdint.h>

// Problem constants (from reference)
#define B_SZ   512
#define T_SZ   100
#define NPRE   256
#define NPOST  256
#define KTOT   (B_SZ * T_SZ)   // 51200

typedef __bf16 bf16x8 __attribute__((ext_vector_type(8)));
typedef float  floatx4 __attribute__((ext_vector_type(4)));

__device__ __forceinline__ uint32_t bf16_rne(float v) {
    uint32_t bits = __float_as_uint(v);
    return (bits + 0x7FFFu + ((bits >> 16) & 1u)) >> 16;
}
__device__ __forceinline__ uint32_t pack_trunc2(float a, float b) {
    return (__float_as_uint(a) >> 16) | (__float_as_uint(b) & 0xFFFF0000u);
}

// ---------------------------------------------------------------------------
// R19 = the R15/R18 pipeline RE-BUDGETED to fit the observed 128-VGPR cap.
// Evidence: R15 (waves_per_eu(2)) and R18 (launch_bounds(256,2)) both pinned
// at VGPR_Count=128 + 178 MB scratch -> ~200-float in-flight footprint can
// never be granted. Yet both sustained 3.4 TB/s (vs R10's 2.0) while hauling
// 320 MB -> the batched-issue pattern drives the memory system well; it only
// needs to FIT. This version: peak live ~110 floats.
//  - scan: 16-float windows, 3 rotating buffers, 2 windows in flight
//  - B: split 24/28; first half issued during scan, second at scan end;
//    phase-1 B hoisted across MFMA0 (scan arrays dead there)
//  - amdgpu_waves_per_eu(2,2): second attempt at a 256 cap (R15's (4,4) was
//    honored as cap=128 -> (2,2) should cap 256); kernel fits 128 regardless.
// Occupancy: LDS 64 KB -> 2 blocks/CU = 8 waves/CU = 2 waves/EU (unchanged).
// Mapping, LDS fragment layout, fp32 scan sequence + RNE pack, MFMA loop,
// partial layout, reduces: bit-identical to R10 (absmax must stay 2.38e-7).
// ---------------------------------------------------------------------------
__device__ __forceinline__ void issue16(const float* src, int tbase, float* x) {
#pragma unroll
    for (int j = 0; j < 16; ++j)
        x[j] = src[(size_t)(tbase + j) * NPRE];
}
// consume one 16-t window -> 8 packed words
__device__ __forceinline__ void consume8(const float* x, float& carry,
                                         uint32_t* pkc, float decay) {
#pragma unroll
    for (int j = 0; j < 8; ++j) {
        uint32_t lo = bf16_rne(carry);   // trace[t]=carry, then update
        carry = decay * (carry + x[2 * j]);
        uint32_t hi = bf16_rne(carry);
        carry = decay * (carry + x[2 * j + 1]);
        pkc[j] = lo | (hi << 16);
    }
}

__device__ __forceinline__ void deposit_A(unsigned short (*A)[512],
                                          const uint32_t* pk, int pg, int lp)
{
#pragma unroll
    for (int kc = 0; kc < 3; ++kc)
#pragma unroll
        for (int w = 0; w < 4; ++w)
            *(uint4*)&A[kc * 8 + pg][(w * 16 + lp) * 8] =
                make_uint4(pk[kc * 16 + w * 4],     pk[kc * 16 + w * 4 + 1],
                           pk[kc * 16 + w * 4 + 2], pk[kc * 16 + w * 4 + 3]);
    // kc = 3: t 96..99 real, 100..127 zero
    *(uint4*)&A[24 + pg][lp * 8] = make_uint4(pk[48], pk[49], 0u, 0u);
#pragma unroll
    for (int w = 1; w < 4; ++w)
        *(uint4*)&A[24 + pg][(w * 16 + lp) * 8] = make_uint4(0u, 0u, 0u, 0u);
}

// B staging split into two sub-batches (keeps in-flight regs low).
// half==0: B1 = t 0..23, B2 = t 24..47.  half==1: B1 = t 48..71, B2 = t 72..99.
__device__ __forceinline__ void load_B1(const float* pb, int half, float* x) {
    const int t0 = half ? 48 : 0;
#pragma unroll
    for (int j = 0; j < 24; ++j)
        x[j] = pb[(size_t)(t0 + j) * NPOST];
}
__device__ __forceinline__ void load_B2(const float* pb, int half, float* x) {
    if (half == 0) {
#pragma unroll
        for (int j = 0; j < 24; ++j)
            x[j] = pb[(size_t)(24 + j) * NPOST];
    } else {
#pragma unroll
        for (int j = 0; j < 28; ++j)
            x[j] = pb[(size_t)(72 + j) * NPOST];
    }
}
__device__ __forceinline__ void store_oct(unsigned short (*Bl)[512], int o,
                                          int qg, int q15, const float* x8)
{
    *(uint4*)&Bl[(o >> 2) * 8 + qg][((o & 3) * 16 + q15) * 8] =
        make_uint4(pack_trunc2(x8[0], x8[1]), pack_trunc2(x8[2], x8[3]),
                   pack_trunc2(x8[4], x8[5]), pack_trunc2(x8[6], x8[7]));
}
__device__ __forceinline__ void store_B1(unsigned short (*Bl)[512], int half,
                                         int qg, int q15, const float* x)
{
    const int ob = half ? 6 : 0;
#pragma unroll
    for (int i = 0; i < 3; ++i)
        store_oct(Bl, ob + i, qg, q15, &x[i * 8]);
}
__device__ __forceinline__ void store_B2(unsigned short (*Bl)[512], int half,
                                         int qg, int q15, const float* x)
{
    if (half == 0) {
#pragma unroll
        for (int i = 0; i < 3; ++i)
            store_oct(Bl, 3 + i, qg, q15, &x[i * 8]);
    } else {
#pragma unroll
        for (int i = 0; i < 3; ++i)
            store_oct(Bl, 9 + i, qg, q15, &x[i * 8]);
        // oct 12: t 96..99 real + zeros; octs 13..15: zero
        *(uint4*)&Bl[24 + qg][q15 * 8] =
            make_uint4(pack_trunc2(x[24], x[25]), pack_trunc2(x[26], x[27]),
                       0u, 0u);
#pragma unroll
        for (int o = 13; o < 16; ++o)
            *(uint4*)&Bl[24 + qg][((o & 3) * 16 + q15) * 8] =
                make_uint4(0u, 0u, 0u, 0u);
    }
}

__global__ __launch_bounds__(256) __attribute__((amdgpu_waves_per_eu(2, 2)))
void stdp_fused_gemm(
    const float* __restrict__ pre, const float* __restrict__ post,
    float* __restrict__ partial)
{
    __shared__ __align__(16) unsigned short A_lds[32][512];  // 32 KB
    __shared__ __align__(16) unsigned short B_lds[32][512];  // 32 KB

    const int bx   = blockIdx.x;      // 0..511
    const int s    = bx & 127;
    const int tile = bx >> 7;         // 0..3
    const int pt   = tile & 1;
    const int qt   = tile >> 1;
    const int tid  = threadIdx.x;     // 0..255
    const int lane = tid & 63, wave = tid >> 6;   // wave = wp (0..3)
    const int l15 = lane & 15, l4 = lane >> 4;

    const int half  = tid >> 7;       // 0/1 (wave-uniform): scan batch / B t-half
    const int p_loc = tid & 127;      // scan row
    const int qloc  = tid & 127;      // B column
    const int qg = qloc >> 4, q15 = qloc & 15;
    const int pg = p_loc >> 4, lp = p_loc & 15;

    const float decay = 0.95122942450071400910f;   // expf(-1/20)

    floatx4 acc[2][8] = {};

    float w0[16], w1[16], w2[16], xt[4];
    float xb1[24], xb2[28];
    uint32_t pk[50];

    // ---- prologue: round-0 scan windows 0,1 in flight ----
    {
        const int b = s * 4 + half;
        const float* src = pre + (size_t)b * (T_SZ * NPRE) + pt * 128 + p_loc;
        issue16(src, 0, w0);
        __builtin_amdgcn_sched_barrier(0);
        issue16(src, 16, w1);
        __builtin_amdgcn_sched_barrier(0);
    }

#pragma unroll
    for (int r = 0; r < 2; ++r) {
        const int b_scan = s * 4 + 2 * r + half;
        const float* src = pre + (size_t)b_scan * (T_SZ * NPRE) + pt * 128 + p_loc;
        const float* pb0 = post + (size_t)(s * 4 + 2 * r) * (T_SZ * NPOST)
                                + qt * 128 + qloc;
        const float* pb1 = post + (size_t)(s * 4 + 2 * r + 1) * (T_SZ * NPOST)
                                + qt * 128 + qloc;
        float carry = 0.0f;

        // ---- scan: 6 windows + tail, 2-deep in flight ----
        issue16(src, 32, w2);                 // wnd2
        __builtin_amdgcn_sched_barrier(0);
        consume8(w0, carry, &pk[0], decay);   // t 0..15

        issue16(src, 48, w0);                 // wnd3
        __builtin_amdgcn_sched_barrier(0);
        consume8(w1, carry, &pk[8], decay);   // t 16..31

        issue16(src, 64, w1);                 // wnd4
        __builtin_amdgcn_sched_barrier(0);
        consume8(w2, carry, &pk[16], decay);  // t 32..47

        issue16(src, 80, w2);                 // wnd5
        load_B1(pb0, half, xb1);              // B phase-0 first half
        __builtin_amdgcn_sched_barrier(0);
        consume8(w0, carry, &pk[24], decay);  // t 48..63

        {                                     // tail t 96..99
#pragma unroll
            for (int j = 0; j < 4; ++j)
                xt[j] = src[(size_t)(96 + j) * NPRE];
        }
        __builtin_amdgcn_sched_barrier(0);
        consume8(w1, carry, &pk[32], decay);  // t 64..79
        consume8(w2, carry, &pk[40], decay);  // t 80..95
#pragma unroll
        for (int j = 0; j < 2; ++j) {
            uint32_t lo = bf16_rne(carry);
            carry = decay * (carry + xt[2 * j]);
            uint32_t hi = bf16_rne(carry);
            carry = decay * (carry + xt[2 * j + 1]);
            pk[48 + j] = lo | (hi << 16);
        }

        load_B2(pb0, half, xb2);              // B phase-0 second half
        __builtin_amdgcn_sched_barrier(0);

        // ---- phase 0 (batch 2r+0) ----
        if (half == 0) deposit_A(A_lds, pk, pg, lp);
        store_B1(B_lds, half, qg, q15, xb1);
        store_B2(B_lds, half, qg, q15, xb2);
        __syncthreads();

        // B loads for phase 1: in flight across MFMA0 (scan arrays dead)
        load_B1(pb1, half, xb1);
        load_B2(pb1, half, xb2);
        __builtin_amdgcn_sched_barrier(0);

#pragma unroll
        for (int kc = 0; kc < 4; ++kc) {
            bf16x8 a[2], bb[8];
#pragma unroll
            for (int f = 0; f < 2; ++f)
                a[f] = *(const bf16x8*)&A_lds[kc * 8 + wave * 2 + f][lane * 8];
#pragma unroll
            for (int g = 0; g < 8; ++g)
                bb[g] = *(const bf16x8*)&B_lds[kc * 8 + g][lane * 8];
#pragma unroll
            for (int f = 0; f < 2; ++f)
#pragma unroll
                for (int g = 0; g < 8; ++g)
                    acc[f][g] = __builtin_amdgcn_mfma_f32_16x16x32_bf16(
                        a[f], bb[g], acc[f][g], 0, 0, 0);
        }
        __syncthreads();

        // ---- phase 1 (batch 2r+1) ----
        if (half == 1) deposit_A(A_lds, pk, pg, lp);
        store_B1(B_lds, half, qg, q15, xb1);
        store_B2(B_lds, half, qg, q15, xb2);
        __syncthreads();

        // round-1 scan windows 0,1: in flight across MFMA1
        if (r == 0) {
            const int bn = s * 4 + 2 + half;
            const float* srcn = pre + (size_t)bn * (T_SZ * NPRE) + pt * 128 + p_loc;
            issue16(srcn, 0, w0);
            __builtin_amdgcn_sched_barrier(0);
            issue16(srcn, 16, w1);
            __builtin_amdgcn_sched_barrier(0);
        }

#pragma unroll
        for (int kc = 0; kc < 4; ++kc) {
            bf16x8 a[2], bb[8];
#pragma unroll
            for (int f = 0; f < 2; ++f)
                a[f] = *(const bf16x8*)&A_lds[kc * 8 + wave * 2 + f][lane * 8];
#pragma unroll
            for (int g = 0; g < 8; ++g)
                bb[g] = *(const bf16x8*)&B_lds[kc * 8 + g][lane * 8];
#pragma unroll
            for (int f = 0; f < 2; ++f)
#pragma unroll
                for (int g = 0; g < 8; ++g)
                    acc[f][g] = __builtin_amdgcn_mfma_f32_16x16x32_bf16(
                        a[f], bb[g], acc[f][g], 0, 0, 0);
        }
        __syncthreads();
    }

    // ---- writeout: partial[bx][p_loc 128][q_loc 128]
    // C/D layout (m89/m91): col = lane&15, row = (lane>>4)*4 + reg
    float* pout = partial + (size_t)bx * (128 * 128);
#pragma unroll
    for (int f = 0; f < 2; ++f) {
        int r0 = wave * 32 + f * 16 + l4 * 4;
#pragma unroll
        for (int g = 0; g < 8; ++g) {
            int c = g * 16 + l15;
#pragma unroll
            for (int v = 0; v < 4; ++v)
                pout[(size_t)(r0 + v) * 128 + c] = acc[f][g][v];
        }
    }
}

// ---------------------------------------------------------------------------
// Reduce stage 1 (R10-proven): partial[bx = tile*128 + s][i], i = p*128+q.
// 2048 blocks x 256 thr; thread t: g = t>>16 (0..7), e = t&65535,
// tile = e>>14; sums s = g*16..+15 (4 indep chains).
// ---------------------------------------------------------------------------
__global__ __launch_bounds__(256) void stdp_reduce1(
    const float* __restrict__ partial, float* __restrict__ tmp)
{
    const int t = blockIdx.x * 256 + threadIdx.x;  // 0..524287
    const int g = t >> 16;                         // 0..7
    const int e = t & 65535;
    const int tile = e >> 14;
    const float* src = partial + ((size_t)(tile * 128 + g * 16) << 14) + (e & 16383);
    float a4[4] = {};
#pragma unroll
    for (int i = 0; i < 4; ++i)
#pragma unroll
        for (int u = 0; u < 4; ++u)
            a4[u] += src[(size_t)(u * 4 + i) << 14];
    tmp[t] = (a4[0] + a4[1]) + (a4[2] + a4[3]);
}

// ---------------------------------------------------------------------------
// Reduce stage 2 (R10-proven): 8 -> 1, un-tile, scale by (A+ - A-)/(B*T).
// ---------------------------------------------------------------------------
__global__ __launch_bounds__(256) void stdp_reduce2(
    const float* __restrict__ tmp, float* __restrict__ out)
{
    const int idx = blockIdx.x * 256 + threadIdx.x;  // 0..65535
    const int P = idx >> 8, Q = idx & 255;
    const int tile = (Q >> 7) * 2 + (P >> 7);
    const int e = (tile << 14) | ((P & 127) << 7) | (Q & 127);
    float a[4];
#pragma unroll
    for (int u = 0; u < 4; ++u)
        a[u] = tmp[(size_t)(2 * u) * 65536 + e] +
               tmp[(size_t)(2 * u + 1) * 65536 + e];
    const float scale = (0.005f - 0.00525f) * (1.0f / (float)KTOT);
    out[idx] = ((a[0] + a[1]) + (a[2] + a[3])) * scale;
}

// ---------------------------------------------------------------------------
extern "C" void kernel_launch(void* const* d_in, const int* in_sizes, int n_in,
                              void* d_out, int out_size, void* d_ws, size_t ws_size,
                              hipStream_t stream)
{
    const float* pre  = (const float*)d_in[0];   // [512,100,256]
    const float* post = (const float*)d_in[1];   // [512,100,256]
    float* out = (float*)d_out;                  // [256,256]

    // ws: partial 33.5 MB | tmp 2 MB
    float* partial = (float*)d_ws;
    float* tmp     = (float*)((char*)d_ws + (size_t)33554432);

    stdp_fused_gemm<<<512, 256, 0, stream>>>(pre, post, partial);
    stdp_reduce1<<<2048, 256, 0, stream>>>(partial, tmp);
    stdp_reduce2<<<256, 256, 0, stream>>>(tmp, out);
}